// Round 4
// baseline (404.227 us; speedup 1.0000x reference)
//
#include <hip/hip_runtime.h>
#include <hip/hip_bf16.h>
#include <cstdint>
#include <cstddef>

typedef __attribute__((ext_vector_type(8))) short short8;
typedef __attribute__((ext_vector_type(16))) float float16;

// Problem constants: B=8, C=512, H=W=14, HS=1024, K=144 centers (12x12), O=9 offsets.

static __device__ __forceinline__ unsigned short f2bf(float f) {
  union { float f; unsigned int u; } v; v.f = f;
  unsigned int r = v.u + 0x7fffu + ((v.u >> 16) & 1u);
  return (unsigned short)(r >> 16);
}

// -------- Kernel 1: projection GEMM --------
// out[h][p] = sum_c w[h][c] * x[b][c][p] + bias[h], for both (w1,b1) and (w2,b2)
// stacked as M=2048. Tiles: 128 h x 64 p per block, K=512 in chunks of 64.
// Writes P[mat][b][h][p] as bf16, p in [0,196).
__global__ __launch_bounds__(256, 2)
void proj_kernel(const float* __restrict__ x,
                 const float* __restrict__ w1, const float* __restrict__ b1,
                 const float* __restrict__ w2, const float* __restrict__ b2,
                 unsigned short* __restrict__ P)
{
  const int nt = blockIdx.x;         // 0..3   p-tile (64)
  const int mt = blockIdx.y;         // 0..15  h-tile (128)
  const int b  = blockIdx.z;         // 0..7
  const int mat = (mt >= 8) ? 1 : 0;
  const float* __restrict__ w    = mat ? w2 : w1;
  const float* __restrict__ bias = mat ? b2 : b1;
  const int h0 = (mt - mat * 8) * 128;   // 0..896 within matrix
  const int p0 = nt * 64;

  __shared__ unsigned short As[128 * 72];  // [h][c], stride 72 (144B, 16B-aligned rows)
  __shared__ unsigned short Bs[64 * 72];   // [p][c]

  const int tid  = threadIdx.x;
  const int lane = tid & 63, wave = tid >> 6;
  const int ln31 = lane & 31, lh = lane >> 5;

  float16 acc0, acc1;
  #pragma unroll
  for (int r = 0; r < 16; ++r) { acc0[r] = 0.f; acc1[r] = 0.f; }

  for (int kc = 0; kc < 512; kc += 64) {
    // stage A (weights): 128 rows x 64 cols, fp32 -> bf16
    #pragma unroll
    for (int i = 0; i < 8; ++i) {
      int idx = tid + i * 256;          // 0..2047 float4s
      int row = idx >> 4;
      int c4  = (idx & 15) << 2;
      const float4 v = *(const float4*)&w[(size_t)(h0 + row) * 512 + kc + c4];
      unsigned short* dst = &As[row * 72 + c4];
      dst[0] = f2bf(v.x); dst[1] = f2bf(v.y); dst[2] = f2bf(v.z); dst[3] = f2bf(v.w);
    }
    // stage B (x): 64 c-rows x 64 p, transposed to [p][c]
    #pragma unroll
    for (int i = 0; i < 16; ++i) {
      int idx = tid + i * 256;          // 0..4095
      int c  = idx >> 6;                // 0..63
      int pl = idx & 63;
      int p  = p0 + pl;
      float val = 0.f;
      if (p < 196) val = x[((size_t)b * 512 + kc + c) * 196 + p];
      Bs[pl * 72 + c] = f2bf(val);
    }
    __syncthreads();
    #pragma unroll
    for (int ks = 0; ks < 4; ++ks) {
      short8 a   = *(const short8*)&As[(wave * 32 + ln31) * 72 + ks * 16 + lh * 8];
      short8 bb0 = *(const short8*)&Bs[(ln31) * 72 + ks * 16 + lh * 8];
      short8 bb1 = *(const short8*)&Bs[(32 + ln31) * 72 + ks * 16 + lh * 8];
      acc0 = __builtin_amdgcn_mfma_f32_32x32x16_bf16(a, bb0, acc0, 0, 0, 0);
      acc1 = __builtin_amdgcn_mfma_f32_32x32x16_bf16(a, bb1, acc1, 0, 0, 0);
    }
    __syncthreads();
  }

  // epilogue: bias add, bf16 convert, store P[mat][b][h][p]
  #pragma unroll
  for (int r = 0; r < 16; ++r) {
    int rowl = (r & 3) + ((r >> 2) << 3) + (lh << 2);
    int h = h0 + wave * 32 + rowl;
    float bi = bias[h];
    size_t base = ((size_t)(mat * 8 + b) * 1024 + h) * 196;
    int p_a = p0 + ln31;
    if (p_a < 196) P[base + p_a] = f2bf(acc0[r] + bi);
    int p_b = p_a + 32;
    if (p_b < 196) P[base + p_b] = f2bf(acc1[r] + bi);
  }
}

// -------- Kernel 2: LDS-staged gather into MFMA-swizzled operand layouts --------
// Block bx in [0,256): cpz work  — b = bx>>5,       rows i0 = (bx&31)*32 from P1
// Block bx in [256,512): spz work — b = (bx-256)>>5, rows j0 = ((bx-256)&31)*32 from P2
// Stage 32 rows x 196 ushorts of P into LDS (coalesced flat dword copy, padded
// row stride 202 ushorts for bank spread), then emit swizzled 16B chunks:
//   cpz chunk ((b*9+s)*1024 + i)*2 + h   = 8 bf16 of cp[b][i][k=16s+8h+e]
//   spz chunk (((o*8+b)*9+s)*1024 + j)*2 + h = 8 bf16 of sp[o][b][j][k]
// where element k maps to P-row position (k/12+1+dy)*14 + (k%12+1+dx).
__global__ __launch_bounds__(256)
void gather_kernel(const unsigned short* __restrict__ P,
                   unsigned short* __restrict__ cpz,
                   unsigned short* __restrict__ spz)
{
  __shared__ unsigned int ldsu[32 * 101];            // 32 rows x 202 ushorts (padded)
  unsigned short* lds = (unsigned short*)ldsu;

  const int bx   = blockIdx.x;
  const int tid  = threadIdx.x;
  const int lane = tid & 63, wave = tid >> 6;
  const bool is_spz = (bx >= 256);
  const int bb = is_spz ? (bx - 256) : bx;
  const int b  = bb >> 5;
  const int r0 = (bb & 31) << 5;                     // row-block start within [0,1024)

  // stage: 32 contiguous rows of 196 ushorts = 3136 dwords, flat coalesced
  // P element offset = ((mat*8 + b)*1024 + r0) * 196   (mat = is_spz)
  const unsigned int* gsrc =
      (const unsigned int*)(P + (((size_t)(is_spz ? 8 : 0) + b) * 1024 + r0) * 196);
  #pragma unroll
  for (int it = 0; it < 13; ++it) {
    int idx = tid + it * 256;
    if (idx < 3136) {
      int row = idx / 98;                            // compiler emits magic-mul
      int dw  = idx - row * 98;
      ldsu[row * 101 + dw] = gsrc[idx];
    }
  }
  __syncthreads();

  const int rl = lane >> 1;                          // row within block (0..31)
  const int h  = lane & 1;

  if (!is_spz) {
    // cpz: 9 s-values; each (s) -> 64 lanes cover (row, h); coalesced 1KB stores
    for (int p = wave; p < 9; p += 4) {
      const int s = p;
      const int kbase = s * 16 + h * 8;
      unsigned short tmp[8];
      #pragma unroll
      for (int e = 0; e < 8; ++e) {
        int k  = kbase + e;
        int ky = (k * 683) >> 13;                    // k/12 for k<144
        int kx = k - ky * 12;
        tmp[e] = lds[rl * 202 + (ky + 1) * 14 + (kx + 1)];
      }
      size_t chunk = ((size_t)(b * 9 + s) * 1024 + r0 + rl) * 2 + h;
      *(uint4*)(cpz + chunk * 8) = *(const uint4*)tmp;
    }
  } else {
    // spz: 81 (o,s) pairs; each pair -> 64 lanes cover (row, h)
    for (int p = wave; p < 81; p += 4) {
      const int o = p / 9;
      const int s = p - o * 9;
      const int dy = o / 3 - 1;
      const int dx = (o - (o / 3) * 3) - 1;
      const int doff = dy * 14 + dx;
      const int kbase = s * 16 + h * 8;
      unsigned short tmp[8];
      #pragma unroll
      for (int e = 0; e < 8; ++e) {
        int k  = kbase + e;
        int ky = (k * 683) >> 13;
        int kx = k - ky * 12;
        tmp[e] = lds[rl * 202 + (ky + 1) * 14 + (kx + 1) + doff];
      }
      size_t chunk = ((size_t)((o * 8 + b) * 9 + s) * 1024 + r0 + rl) * 2 + h;
      *(uint4*)(spz + chunk * 8) = *(const uint4*)tmp;
    }
  }
}

// -------- Kernel 3: cofe GEMM + fused row-normalization --------
// 1-D grid of 2304 blocks with bijective XCD-chunked swizzle: XCD k owns 288
// consecutive swizzled ids = 9 complete (b,o) slices, so each 288 KB spz slice
// is fetched from HBM by exactly ONE XCD's L2 (was: all 8).
// Decoded block = (iblk 0..31, o 0..8, b 0..7): 32 rows x 1024 cols of cofe[b][o].
// 4 waves, each 8 tiles of 32x32 along j; K=144 = 9 MFMA(32x32x16) steps.
__global__ __launch_bounds__(256, 2)
void cofe_kernel(const unsigned short* __restrict__ cpz,
                 const unsigned short* __restrict__ spz,
                 float* __restrict__ out)
{
  // bijective chunked swizzle (2304 = 8 XCDs * 288)
  const int bid = blockIdx.x;
  const int swz = (bid & 7) * 288 + (bid >> 3);
  const int iblk = swz & 31;
  const int ob   = swz >> 5;        // b*9 + o
  const int o    = ob % 9;
  const int b    = ob / 9;
  const int tid  = threadIdx.x;
  const int lane = tid & 63, wave = tid >> 6;
  const int ln31 = lane & 31, lh = lane >> 5;
  const int i0 = iblk << 5;
  const int jw = wave << 8;

  float16 acc[8];
  #pragma unroll
  for (int t = 0; t < 8; ++t) {
    #pragma unroll
    for (int r = 0; r < 16; ++r) acc[t][r] = 0.f;
  }

  const uint4* A  = (const uint4*)cpz;
  const uint4* Bp = (const uint4*)spz;
  const size_t abase = ((size_t)b * 9 * 1024 + i0 + ln31) * 2 + lh;
  const size_t bbase = ((size_t)(o * 8 + b) * 9 * 1024 + jw + ln31) * 2 + lh;

  #pragma unroll
  for (int s = 0; s < 9; ++s) {
    short8 a = *(const short8*)(A + abase + (size_t)s * 2048);
    #pragma unroll
    for (int t = 0; t < 8; ++t) {
      short8 bb = *(const short8*)(Bp + bbase + (size_t)s * 2048 + t * 64);
      acc[t] = __builtin_amdgcn_mfma_f32_32x32x16_bf16(a, bb, acc[t], 0, 0, 0);
    }
  }

  // per-row sum of squares over this wave's 256 cols
  float ssq[16];
  #pragma unroll
  for (int r = 0; r < 16; ++r) {
    float s2 = 0.f;
    #pragma unroll
    for (int t = 0; t < 8; ++t) s2 += acc[t][r] * acc[t][r];
    ssq[r] = s2;
  }
  // butterfly across the 32 cols (stays within each 32-lane half)
  #pragma unroll
  for (int m = 1; m <= 16; m <<= 1) {
    #pragma unroll
    for (int r = 0; r < 16; ++r) ssq[r] += __shfl_xor(ssq[r], m, 64);
  }

  __shared__ float s_ssq[32];
  if (tid < 32) s_ssq[tid] = 0.f;
  __syncthreads();
  if (ln31 == 0) {          // lanes 0 and 32 of each wave hold the half-sums
    #pragma unroll
    for (int r = 0; r < 16; ++r) {
      int rowl = (r & 3) + ((r >> 2) << 3) + (lh << 2);
      atomicAdd(&s_ssq[rowl], ssq[r]);
    }
  }
  __syncthreads();

  const size_t outbase = ((size_t)(b * 9 + o) << 20) + ((size_t)i0 << 10) + jw + ln31;
  #pragma unroll
  for (int r = 0; r < 16; ++r) {
    int rowl = (r & 3) + ((r >> 2) << 3) + (lh << 2);
    float nrm = sqrtf(s_ssq[rowl]);
    float sc = 1.f / fmaxf(nrm, 1e-12f);
    size_t rb = outbase + ((size_t)rowl << 10);
    #pragma unroll
    for (int t = 0; t < 8; ++t)
      __builtin_nontemporal_store(acc[t][r] * sc, &out[rb + (t << 5)]);
  }
}

extern "C" void kernel_launch(void* const* d_in, const int* in_sizes, int n_in,
                              void* d_out, int out_size, void* d_ws, size_t ws_size,
                              hipStream_t stream)
{
  const float* x  = (const float*)d_in[0];
  const float* w1 = (const float*)d_in[1];
  const float* b1 = (const float*)d_in[2];
  const float* w2 = (const float*)d_in[3];
  const float* b2 = (const float*)d_in[4];
  float* out = (float*)d_out;

  // workspace layout (bf16 as ushort):
  // P   : [2][8][1024][196]          = 3,211,264 elems
  // cpz : [8][9][1024][2][8]         = 1,179,648 elems
  // spz : [9][8][9][1024][2][8]      = 10,616,832 elems   (~30 MB total)
  unsigned short* P   = (unsigned short*)d_ws;
  unsigned short* cpz = P + (size_t)2 * 8 * 1024 * 196;
  unsigned short* spz = cpz + (size_t)8 * 9 * 1024 * 16;

  proj_kernel<<<dim3(4, 16, 8), 256, 0, stream>>>(x, w1, b1, w2, b2, P);
  gather_kernel<<<dim3(512), 256, 0, stream>>>(P, cpz, spz);
  cofe_kernel<<<dim3(2304), 256, 0, stream>>>(cpz, spz, out);
}

// Round 5
// 386.349 us; speedup vs baseline: 1.0463x; 1.0463x over previous
//
#include <hip/hip_runtime.h>
#include <hip/hip_bf16.h>
#include <cstdint>
#include <cstddef>

typedef __attribute__((ext_vector_type(8))) short short8;
typedef __attribute__((ext_vector_type(16))) float float16;

// Problem constants: B=8, C=512, H=W=14, HS=1024, K=144 centers (12x12), O=9 offsets.

static __device__ __forceinline__ unsigned short f2bf(float f) {
  union { float f; unsigned int u; } v; v.f = f;
  unsigned int r = v.u + 0x7fffu + ((v.u >> 16) & 1u);
  return (unsigned short)(r >> 16);
}

// -------- Kernel 1: projection GEMM --------
// out[h][p] = sum_c w[h][c] * x[b][c][p] + bias[h], for both (w1,b1) and (w2,b2)
// stacked as M=2048. Tiles: 128 h x 64 p per block, K=512 in chunks of 64.
// Writes P[mat][b][h][p] as bf16, p in [0,196).
__global__ __launch_bounds__(256, 2)
void proj_kernel(const float* __restrict__ x,
                 const float* __restrict__ w1, const float* __restrict__ b1,
                 const float* __restrict__ w2, const float* __restrict__ b2,
                 unsigned short* __restrict__ P)
{
  const int nt = blockIdx.x;         // 0..3   p-tile (64)
  const int mt = blockIdx.y;         // 0..15  h-tile (128)
  const int b  = blockIdx.z;         // 0..7
  const int mat = (mt >= 8) ? 1 : 0;
  const float* __restrict__ w    = mat ? w2 : w1;
  const float* __restrict__ bias = mat ? b2 : b1;
  const int h0 = (mt - mat * 8) * 128;   // 0..896 within matrix
  const int p0 = nt * 64;

  __shared__ unsigned short As[128 * 72];  // [h][c], stride 72 (144B, 16B-aligned rows)
  __shared__ unsigned short Bs[64 * 72];   // [p][c]

  const int tid  = threadIdx.x;
  const int lane = tid & 63, wave = tid >> 6;
  const int ln31 = lane & 31, lh = lane >> 5;

  float16 acc0, acc1;
  #pragma unroll
  for (int r = 0; r < 16; ++r) { acc0[r] = 0.f; acc1[r] = 0.f; }

  for (int kc = 0; kc < 512; kc += 64) {
    // stage A (weights): 128 rows x 64 cols, fp32 -> bf16 (compiler merges 4 u16 -> b64)
    #pragma unroll
    for (int i = 0; i < 8; ++i) {
      int idx = tid + i * 256;          // 0..2047 float4s
      int row = idx >> 4;
      int c4  = (idx & 15) << 2;
      const float4 v = *(const float4*)&w[(size_t)(h0 + row) * 512 + kc + c4];
      unsigned short* dst = &As[row * 72 + c4];
      dst[0] = f2bf(v.x); dst[1] = f2bf(v.y); dst[2] = f2bf(v.z); dst[3] = f2bf(v.w);
    }
    // stage B (x): 64 c-rows x 64 p, transposed to [p][c].
    // Thread packs 4 c-values at one p: 4 coalesced stride-196 loads -> one b64 LDS write
    // (was: 16 scalar u16 writes/thread/chunk at 8-way bank conflict).
    #pragma unroll
    for (int i = 0; i < 4; ++i) {
      int idx = tid + i * 256;          // 0..1023
      int p   = idx & 63;
      int c4  = (idx >> 6) << 2;        // 0,4,...,60
      int gp  = p0 + p;
      float v0 = 0.f, v1 = 0.f, v2 = 0.f, v3 = 0.f;
      if (gp < 196) {
        const float* xb = &x[((size_t)b * 512 + kc + c4) * 196 + gp];
        v0 = xb[0]; v1 = xb[196]; v2 = xb[392]; v3 = xb[588];
      }
      union { unsigned short us[4]; unsigned long long u64; } pk;
      pk.us[0] = f2bf(v0); pk.us[1] = f2bf(v1); pk.us[2] = f2bf(v2); pk.us[3] = f2bf(v3);
      *(unsigned long long*)&Bs[p * 72 + c4] = pk.u64;
    }
    __syncthreads();
    #pragma unroll
    for (int ks = 0; ks < 4; ++ks) {
      short8 a   = *(const short8*)&As[(wave * 32 + ln31) * 72 + ks * 16 + lh * 8];
      short8 bb0 = *(const short8*)&Bs[(ln31) * 72 + ks * 16 + lh * 8];
      short8 bb1 = *(const short8*)&Bs[(32 + ln31) * 72 + ks * 16 + lh * 8];
      acc0 = __builtin_amdgcn_mfma_f32_32x32x16_bf16(a, bb0, acc0, 0, 0, 0);
      acc1 = __builtin_amdgcn_mfma_f32_32x32x16_bf16(a, bb1, acc1, 0, 0, 0);
    }
    __syncthreads();
  }

  // epilogue: bias add, bf16 convert, store P[mat][b][h][p]
  #pragma unroll
  for (int r = 0; r < 16; ++r) {
    int rowl = (r & 3) + ((r >> 2) << 3) + (lh << 2);
    int h = h0 + wave * 32 + rowl;
    float bi = bias[h];
    size_t base = ((size_t)(mat * 8 + b) * 1024 + h) * 196;
    int p_a = p0 + ln31;
    if (p_a < 196) P[base + p_a] = f2bf(acc0[r] + bi);
    int p_b = p_a + 32;
    if (p_b < 196) P[base + p_b] = f2bf(acc1[r] + bi);
  }
}

// -------- Kernel 2: LDS-staged gather into MFMA-swizzled operand layouts --------
// Grid 1024 blocks:
//   bx in [0,256):        cpz — b = bx>>5, rows r0 = (bx&31)*32 from P1, 9 s-values
//   bx in [256,1024):     spz — og = (bx-256)>>8 selects o-group of 3; bb = (bx-256)&255
//                         gives (b, r0); 27 (o,s) pairs per block (load-balanced vs 81).
// Stage 32 rows x 196 ushorts of P into LDS (coalesced dword copy, padded row
// stride 202 ushorts), then emit swizzled 16B chunks:
//   cpz chunk ((b*9+s)*1024 + i)*2 + h      = 8 bf16 of cp[b][i][k=16s+8h+e]
//   spz chunk (((o*8+b)*9+s)*1024 + j)*2 + h = 8 bf16 of sp[o][b][j][k]
// where element k maps to P-row position (k/12+1+dy)*14 + (k%12+1+dx).
__global__ __launch_bounds__(256)
void gather_kernel(const unsigned short* __restrict__ P,
                   unsigned short* __restrict__ cpz,
                   unsigned short* __restrict__ spz)
{
  __shared__ unsigned int ldsu[32 * 101];            // 32 rows x 202 ushorts (padded)
  unsigned short* lds = (unsigned short*)ldsu;

  const int bx   = blockIdx.x;
  const int tid  = threadIdx.x;
  const int lane = tid & 63, wave = tid >> 6;
  const bool is_spz = (bx >= 256);
  const int ix = is_spz ? (bx - 256) : bx;           // spz: 0..767
  const int og = is_spz ? (ix >> 8) : 0;             // o-group 0..2
  const int bb = is_spz ? (ix & 255) : ix;
  const int b  = bb >> 5;
  const int r0 = (bb & 31) << 5;                     // row-block start within [0,1024)

  // stage: 32 contiguous rows of 196 ushorts = 3136 dwords, flat coalesced
  const unsigned int* gsrc =
      (const unsigned int*)(P + (((size_t)(is_spz ? 8 : 0) + b) * 1024 + r0) * 196);
  #pragma unroll
  for (int it = 0; it < 13; ++it) {
    int idx = tid + it * 256;
    if (idx < 3136) {
      int row = idx / 98;                            // compiler emits magic-mul
      int dw  = idx - row * 98;
      ldsu[row * 101 + dw] = gsrc[idx];
    }
  }
  __syncthreads();

  const int rl = lane >> 1;                          // row within block (0..31)
  const int h  = lane & 1;

  if (!is_spz) {
    // cpz: 9 s-values; each (s) -> 64 lanes cover (row, h); coalesced 1KB stores
    for (int p = wave; p < 9; p += 4) {
      const int s = p;
      const int kbase = s * 16 + h * 8;
      unsigned short tmp[8];
      #pragma unroll
      for (int e = 0; e < 8; ++e) {
        int k  = kbase + e;
        int ky = (k * 683) >> 13;                    // k/12 for k<144
        int kx = k - ky * 12;
        tmp[e] = lds[rl * 202 + (ky + 1) * 14 + (kx + 1)];
      }
      size_t chunk = ((size_t)(b * 9 + s) * 1024 + r0 + rl) * 2 + h;
      *(uint4*)(cpz + chunk * 8) = *(const uint4*)tmp;
    }
  } else {
    // spz: this block's 27 (o,s) pairs within o-group og
    for (int p = wave; p < 27; p += 4) {
      const int o = og * 3 + p / 9;
      const int s = p % 9;
      const int dy = o / 3 - 1;
      const int dx = (o - (o / 3) * 3) - 1;
      const int doff = dy * 14 + dx;
      const int kbase = s * 16 + h * 8;
      unsigned short tmp[8];
      #pragma unroll
      for (int e = 0; e < 8; ++e) {
        int k  = kbase + e;
        int ky = (k * 683) >> 13;
        int kx = k - ky * 12;
        tmp[e] = lds[rl * 202 + (ky + 1) * 14 + (kx + 1) + doff];
      }
      size_t chunk = ((size_t)((o * 8 + b) * 9 + s) * 1024 + r0 + rl) * 2 + h;
      *(uint4*)(spz + chunk * 8) = *(const uint4*)tmp;
    }
  }
}

// -------- Kernel 3: cofe GEMM + fused row-normalization --------
// 1-D grid of 2304 blocks (bijective XCD-chunked swizzle), 512 threads = 8 waves.
// Decoded block = (iblk 0..31, o 0..8, b 0..7): 32 rows x 1024 cols of cofe[b][o].
// Each wave: 4 tiles of 32x32 along j (128 cols); acc = 64 VGPR, freeing regs so
// the compiler can keep 2-3 s-steps of L2 loads in flight. K=144 = 9 MFMA steps.
__global__ __launch_bounds__(512, 2)
void cofe_kernel(const unsigned short* __restrict__ cpz,
                 const unsigned short* __restrict__ spz,
                 float* __restrict__ out)
{
  // bijective chunked swizzle (2304 = 8 XCDs * 288)
  const int bid = blockIdx.x;
  const int swz = (bid & 7) * 288 + (bid >> 3);
  const int iblk = swz & 31;
  const int ob   = swz >> 5;        // b*9 + o
  const int o    = ob % 9;
  const int b    = ob / 9;
  const int tid  = threadIdx.x;
  const int lane = tid & 63, wave = tid >> 6;   // wave 0..7
  const int ln31 = lane & 31, lh = lane >> 5;
  const int i0 = iblk << 5;
  const int jw = wave << 7;                     // 128 cols per wave

  float16 acc[4];
  #pragma unroll
  for (int t = 0; t < 4; ++t) {
    #pragma unroll
    for (int r = 0; r < 16; ++r) acc[t][r] = 0.f;
  }

  const uint4* A  = (const uint4*)cpz;
  const uint4* Bp = (const uint4*)spz;
  const size_t abase = ((size_t)b * 9 * 1024 + i0 + ln31) * 2 + lh;
  const size_t bbase = ((size_t)(o * 8 + b) * 9 * 1024 + jw + ln31) * 2 + lh;

  #pragma unroll
  for (int s = 0; s < 9; ++s) {
    short8 a = *(const short8*)(A + abase + (size_t)s * 2048);
    #pragma unroll
    for (int t = 0; t < 4; ++t) {
      short8 bb = *(const short8*)(Bp + bbase + (size_t)s * 2048 + t * 64);
      acc[t] = __builtin_amdgcn_mfma_f32_32x32x16_bf16(a, bb, acc[t], 0, 0, 0);
    }
  }

  // per-row sum of squares over this wave's 128 cols
  float ssq[16];
  #pragma unroll
  for (int r = 0; r < 16; ++r) {
    float s2 = 0.f;
    #pragma unroll
    for (int t = 0; t < 4; ++t) s2 += acc[t][r] * acc[t][r];
    ssq[r] = s2;
  }
  // butterfly across the 32 cols (stays within each 32-lane half)
  #pragma unroll
  for (int m = 1; m <= 16; m <<= 1) {
    #pragma unroll
    for (int r = 0; r < 16; ++r) ssq[r] += __shfl_xor(ssq[r], m, 64);
  }

  __shared__ float s_ssq[32];
  if (tid < 32) s_ssq[tid] = 0.f;
  __syncthreads();
  if (ln31 == 0) {          // lanes 0 and 32 of each wave hold the half-sums
    #pragma unroll
    for (int r = 0; r < 16; ++r) {
      int rowl = (r & 3) + ((r >> 2) << 3) + (lh << 2);
      atomicAdd(&s_ssq[rowl], ssq[r]);
    }
  }
  __syncthreads();

  const size_t outbase = ((size_t)(b * 9 + o) << 20) + ((size_t)i0 << 10) + jw + ln31;
  #pragma unroll
  for (int r = 0; r < 16; ++r) {
    int rowl = (r & 3) + ((r >> 2) << 3) + (lh << 2);
    float nrm = sqrtf(s_ssq[rowl]);
    float sc = 1.f / fmaxf(nrm, 1e-12f);
    size_t rb = outbase + ((size_t)rowl << 10);
    #pragma unroll
    for (int t = 0; t < 4; ++t)
      __builtin_nontemporal_store(acc[t][r] * sc, &out[rb + (t << 5)]);
  }
}

extern "C" void kernel_launch(void* const* d_in, const int* in_sizes, int n_in,
                              void* d_out, int out_size, void* d_ws, size_t ws_size,
                              hipStream_t stream)
{
  const float* x  = (const float*)d_in[0];
  const float* w1 = (const float*)d_in[1];
  const float* b1 = (const float*)d_in[2];
  const float* w2 = (const float*)d_in[3];
  const float* b2 = (const float*)d_in[4];
  float* out = (float*)d_out;

  // workspace layout (bf16 as ushort):
  // P   : [2][8][1024][196]          = 3,211,264 elems
  // cpz : [8][9][1024][2][8]         = 1,179,648 elems
  // spz : [9][8][9][1024][2][8]      = 10,616,832 elems   (~30 MB total)
  unsigned short* P   = (unsigned short*)d_ws;
  unsigned short* cpz = P + (size_t)2 * 8 * 1024 * 196;
  unsigned short* spz = cpz + (size_t)8 * 9 * 1024 * 16;

  proj_kernel<<<dim3(4, 16, 8), 256, 0, stream>>>(x, w1, b1, w2, b2, P);
  gather_kernel<<<dim3(1024), 256, 0, stream>>>(P, cpz, spz);
  cofe_kernel<<<dim3(2304), 512, 0, stream>>>(cpz, spz, out);
}

// Round 6
// 385.299 us; speedup vs baseline: 1.0491x; 1.0027x over previous
//
#include <hip/hip_runtime.h>
#include <hip/hip_bf16.h>
#include <cstdint>
#include <cstddef>

typedef __attribute__((ext_vector_type(8))) short short8;
typedef __attribute__((ext_vector_type(16))) float float16;

// Problem constants: B=8, C=512, H=W=14, HS=1024, K=144 centers (12x12), O=9 offsets.

static __device__ __forceinline__ unsigned short f2bf(float f) {
  union { float f; unsigned int u; } v; v.f = f;
  unsigned int r = v.u + 0x7fffu + ((v.u >> 16) & 1u);
  return (unsigned short)(r >> 16);
}

// -------- Kernel 1: projection GEMM --------
// out[h][p] = sum_c w[h][c] * x[b][c][p] + bias[h], for both (w1,b1) and (w2,b2)
// stacked as M=2048. Tiles: 128 h x 64 p per block, K=512 in chunks of 64.
// Flat 512-block grid with bijective XCD-chunk swizzle (512 = 8 XCDs * 64):
// XCD k owns swz in [k*64,(k+1)*64) -> b == k (x[b] stays in one L2), and the
// 4 nt-siblings of each mt are consecutive -> w-panel shared in L2.
// Writes P[mat][b][h][p] as bf16, p in [0,196).
__global__ __launch_bounds__(256, 2)
void proj_kernel(const float* __restrict__ x,
                 const float* __restrict__ w1, const float* __restrict__ b1,
                 const float* __restrict__ w2, const float* __restrict__ b2,
                 unsigned short* __restrict__ P)
{
  const int bid = blockIdx.x;
  const int swz = (bid & 7) * 64 + (bid >> 3);   // bijective chunk swizzle
  const int b   = swz >> 6;          // 0..7  (one per XCD)
  const int mt  = (swz >> 2) & 15;   // 0..15 h-tile (128)
  const int nt  = swz & 3;           // 0..3  p-tile (64)
  const int mat = (mt >= 8) ? 1 : 0;
  const float* __restrict__ w    = mat ? w2 : w1;
  const float* __restrict__ bias = mat ? b2 : b1;
  const int h0 = (mt - mat * 8) * 128;   // 0..896 within matrix
  const int p0 = nt * 64;

  __shared__ unsigned short As[128 * 72];  // [h][c], stride 72 (144B, 16B-aligned rows)
  __shared__ unsigned short Bs[64 * 72];   // [p][c]

  const int tid  = threadIdx.x;
  const int lane = tid & 63, wave = tid >> 6;
  const int ln31 = lane & 31, lh = lane >> 5;

  float16 acc0, acc1;
  #pragma unroll
  for (int r = 0; r < 16; ++r) { acc0[r] = 0.f; acc1[r] = 0.f; }

  for (int kc = 0; kc < 512; kc += 64) {
    // stage A (weights): 128 rows x 64 cols, fp32 -> bf16 (compiler merges 4 u16 -> b64)
    #pragma unroll
    for (int i = 0; i < 8; ++i) {
      int idx = tid + i * 256;          // 0..2047 float4s
      int row = idx >> 4;
      int c4  = (idx & 15) << 2;
      const float4 v = *(const float4*)&w[(size_t)(h0 + row) * 512 + kc + c4];
      unsigned short* dst = &As[row * 72 + c4];
      dst[0] = f2bf(v.x); dst[1] = f2bf(v.y); dst[2] = f2bf(v.z); dst[3] = f2bf(v.w);
    }
    // stage B (x): 64 c-rows x 64 p, transposed to [p][c].
    // Thread packs 4 c-values at one p: 4 coalesced stride-196 loads -> one b64 LDS write.
    #pragma unroll
    for (int i = 0; i < 4; ++i) {
      int idx = tid + i * 256;          // 0..1023
      int p   = idx & 63;
      int c4  = (idx >> 6) << 2;        // 0,4,...,60
      int gp  = p0 + p;
      float v0 = 0.f, v1 = 0.f, v2 = 0.f, v3 = 0.f;
      if (gp < 196) {
        const float* xb = &x[((size_t)b * 512 + kc + c4) * 196 + gp];
        v0 = xb[0]; v1 = xb[196]; v2 = xb[392]; v3 = xb[588];
      }
      union { unsigned short us[4]; unsigned long long u64; } pk;
      pk.us[0] = f2bf(v0); pk.us[1] = f2bf(v1); pk.us[2] = f2bf(v2); pk.us[3] = f2bf(v3);
      *(unsigned long long*)&Bs[p * 72 + c4] = pk.u64;
    }
    __syncthreads();
    #pragma unroll
    for (int ks = 0; ks < 4; ++ks) {
      short8 a   = *(const short8*)&As[(wave * 32 + ln31) * 72 + ks * 16 + lh * 8];
      short8 bb0 = *(const short8*)&Bs[(ln31) * 72 + ks * 16 + lh * 8];
      short8 bb1 = *(const short8*)&Bs[(32 + ln31) * 72 + ks * 16 + lh * 8];
      acc0 = __builtin_amdgcn_mfma_f32_32x32x16_bf16(a, bb0, acc0, 0, 0, 0);
      acc1 = __builtin_amdgcn_mfma_f32_32x32x16_bf16(a, bb1, acc1, 0, 0, 0);
    }
    __syncthreads();
  }

  // epilogue: bias add, bf16 convert, store P[mat][b][h][p]
  #pragma unroll
  for (int r = 0; r < 16; ++r) {
    int rowl = (r & 3) + ((r >> 2) << 3) + (lh << 2);
    int h = h0 + wave * 32 + rowl;
    float bi = bias[h];
    size_t base = ((size_t)(mat * 8 + b) * 1024 + h) * 196;
    int p_a = p0 + ln31;
    if (p_a < 196) P[base + p_a] = f2bf(acc0[r] + bi);
    int p_b = p_a + 32;
    if (p_b < 196) P[base + p_b] = f2bf(acc1[r] + bi);
  }
}

// -------- Kernel 2: LDS-staged gather into MFMA-swizzled operand layouts --------
// Flat 1024-block grid with bijective XCD-chunk swizzle (1024 = 8 * 128) so
// blocks reading the same P half/batch cluster on the same XCD's L2.
// Decoded id sx:
//   sx in [0,256):        cpz — b = sx>>5, rows r0 = (sx&31)*32 from P1, 9 s-values
//   sx in [256,1024):     spz — og = (sx-256)>>8 selects o-group of 3; bb = (sx-256)&255
//                         gives (b, r0); 27 (o,s) pairs per block.
// Stage 32 rows x 196 ushorts of P into LDS (coalesced dword copy, padded row
// stride 202 ushorts), then emit swizzled 16B chunks:
//   cpz chunk ((b*9+s)*1024 + i)*2 + h      = 8 bf16 of cp[b][i][k=16s+8h+e]
//   spz chunk (((o*8+b)*9+s)*1024 + j)*2 + h = 8 bf16 of sp[o][b][j][k]
// where element k maps to P-row position (k/12+1+dy)*14 + (k%12+1+dx).
__global__ __launch_bounds__(256)
void gather_kernel(const unsigned short* __restrict__ P,
                   unsigned short* __restrict__ cpz,
                   unsigned short* __restrict__ spz)
{
  __shared__ unsigned int ldsu[32 * 101];            // 32 rows x 202 ushorts (padded)
  unsigned short* lds = (unsigned short*)ldsu;

  const int bid  = blockIdx.x;
  const int sx   = (bid & 7) * 128 + (bid >> 3);     // bijective chunk swizzle
  const int tid  = threadIdx.x;
  const int lane = tid & 63, wave = tid >> 6;
  const bool is_spz = (sx >= 256);
  const int ix = is_spz ? (sx - 256) : sx;           // spz: 0..767
  const int og = is_spz ? (ix >> 8) : 0;             // o-group 0..2
  const int bb = is_spz ? (ix & 255) : ix;
  const int b  = bb >> 5;
  const int r0 = (bb & 31) << 5;                     // row-block start within [0,1024)

  // stage: 32 contiguous rows of 196 ushorts = 3136 dwords, flat coalesced
  const unsigned int* gsrc =
      (const unsigned int*)(P + (((size_t)(is_spz ? 8 : 0) + b) * 1024 + r0) * 196);
  #pragma unroll
  for (int it = 0; it < 13; ++it) {
    int idx = tid + it * 256;
    if (idx < 3136) {
      int row = idx / 98;                            // compiler emits magic-mul
      int dw  = idx - row * 98;
      ldsu[row * 101 + dw] = gsrc[idx];
    }
  }
  __syncthreads();

  const int rl = lane >> 1;                          // row within block (0..31)
  const int h  = lane & 1;

  if (!is_spz) {
    // cpz: 9 s-values; each (s) -> 64 lanes cover (row, h); coalesced 1KB stores
    for (int p = wave; p < 9; p += 4) {
      const int s = p;
      const int kbase = s * 16 + h * 8;
      unsigned short tmp[8];
      #pragma unroll
      for (int e = 0; e < 8; ++e) {
        int k  = kbase + e;
        int ky = (k * 683) >> 13;                    // k/12 for k<144
        int kx = k - ky * 12;
        tmp[e] = lds[rl * 202 + (ky + 1) * 14 + (kx + 1)];
      }
      size_t chunk = ((size_t)(b * 9 + s) * 1024 + r0 + rl) * 2 + h;
      *(uint4*)(cpz + chunk * 8) = *(const uint4*)tmp;
    }
  } else {
    // spz: this block's 27 (o,s) pairs within o-group og
    for (int p = wave; p < 27; p += 4) {
      const int o = og * 3 + p / 9;
      const int s = p % 9;
      const int dy = o / 3 - 1;
      const int dx = (o - (o / 3) * 3) - 1;
      const int doff = dy * 14 + dx;
      const int kbase = s * 16 + h * 8;
      unsigned short tmp[8];
      #pragma unroll
      for (int e = 0; e < 8; ++e) {
        int k  = kbase + e;
        int ky = (k * 683) >> 13;
        int kx = k - ky * 12;
        tmp[e] = lds[rl * 202 + (ky + 1) * 14 + (kx + 1) + doff];
      }
      size_t chunk = ((size_t)((o * 8 + b) * 9 + s) * 1024 + r0 + rl) * 2 + h;
      *(uint4*)(spz + chunk * 8) = *(const uint4*)tmp;
    }
  }
}

// -------- Kernel 3: cofe GEMM + fused row-normalization --------
// 1-D grid of 2304 blocks (bijective XCD-chunked swizzle), 512 threads = 8 waves.
// Decoded block = (iblk 0..31, o 0..8, b 0..7): 32 rows x 1024 cols of cofe[b][o].
// Each wave: 4 tiles of 32x32 along j (128 cols). K=144 = 9 MFMA steps.
// __launch_bounds__(512,4): cap VGPR at 128 (acc=64 + operands ~110 fits) to
// guarantee 2 blocks/CU = 32 waves/CU for store-latency overlap.
__global__ __launch_bounds__(512, 4)
void cofe_kernel(const unsigned short* __restrict__ cpz,
                 const unsigned short* __restrict__ spz,
                 float* __restrict__ out)
{
  // bijective chunked swizzle (2304 = 8 XCDs * 288): XCD k handles b==k mostly
  const int bid = blockIdx.x;
  const int swz = (bid & 7) * 288 + (bid >> 3);
  const int iblk = swz & 31;
  const int ob   = swz >> 5;        // b*9 + o
  const int o    = ob % 9;
  const int b    = ob / 9;
  const int tid  = threadIdx.x;
  const int lane = tid & 63, wave = tid >> 6;   // wave 0..7
  const int ln31 = lane & 31, lh = lane >> 5;
  const int i0 = iblk << 5;
  const int jw = wave << 7;                     // 128 cols per wave

  float16 acc[4];
  #pragma unroll
  for (int t = 0; t < 4; ++t) {
    #pragma unroll
    for (int r = 0; r < 16; ++r) acc[t][r] = 0.f;
  }

  const uint4* A  = (const uint4*)cpz;
  const uint4* Bp = (const uint4*)spz;
  const size_t abase = ((size_t)b * 9 * 1024 + i0 + ln31) * 2 + lh;
  const size_t bbase = ((size_t)(o * 8 + b) * 9 * 1024 + jw + ln31) * 2 + lh;

  #pragma unroll
  for (int s = 0; s < 9; ++s) {
    short8 a = *(const short8*)(A + abase + (size_t)s * 2048);
    #pragma unroll
    for (int t = 0; t < 4; ++t) {
      short8 bb = *(const short8*)(Bp + bbase + (size_t)s * 2048 + t * 64);
      acc[t] = __builtin_amdgcn_mfma_f32_32x32x16_bf16(a, bb, acc[t], 0, 0, 0);
    }
  }

  // per-row sum of squares over this wave's 128 cols
  float ssq[16];
  #pragma unroll
  for (int r = 0; r < 16; ++r) {
    float s2 = 0.f;
    #pragma unroll
    for (int t = 0; t < 4; ++t) s2 += acc[t][r] * acc[t][r];
    ssq[r] = s2;
  }
  // butterfly across the 32 cols (stays within each 32-lane half)
  #pragma unroll
  for (int m = 1; m <= 16; m <<= 1) {
    #pragma unroll
    for (int r = 0; r < 16; ++r) ssq[r] += __shfl_xor(ssq[r], m, 64);
  }

  __shared__ float s_ssq[32];
  if (tid < 32) s_ssq[tid] = 0.f;
  __syncthreads();
  if (ln31 == 0) {          // lanes 0 and 32 of each wave hold the half-sums
    #pragma unroll
    for (int r = 0; r < 16; ++r) {
      int rowl = (r & 3) + ((r >> 2) << 3) + (lh << 2);
      atomicAdd(&s_ssq[rowl], ssq[r]);
    }
  }
  __syncthreads();

  const size_t outbase = ((size_t)(b * 9 + o) << 20) + ((size_t)i0 << 10) + jw + ln31;
  #pragma unroll
  for (int r = 0; r < 16; ++r) {
    int rowl = (r & 3) + ((r >> 2) << 3) + (lh << 2);
    float nrm = sqrtf(s_ssq[rowl]);
    float sc = 1.f / fmaxf(nrm, 1e-12f);
    size_t rb = outbase + ((size_t)rowl << 10);
    #pragma unroll
    for (int t = 0; t < 4; ++t)
      __builtin_nontemporal_store(acc[t][r] * sc, &out[rb + (t << 5)]);
  }
}

extern "C" void kernel_launch(void* const* d_in, const int* in_sizes, int n_in,
                              void* d_out, int out_size, void* d_ws, size_t ws_size,
                              hipStream_t stream)
{
  const float* x  = (const float*)d_in[0];
  const float* w1 = (const float*)d_in[1];
  const float* b1 = (const float*)d_in[2];
  const float* w2 = (const float*)d_in[3];
  const float* b2 = (const float*)d_in[4];
  float* out = (float*)d_out;

  // workspace layout (bf16 as ushort):
  // P   : [2][8][1024][196]          = 3,211,264 elems
  // cpz : [8][9][1024][2][8]         = 1,179,648 elems
  // spz : [9][8][9][1024][2][8]      = 10,616,832 elems   (~30 MB total)
  unsigned short* P   = (unsigned short*)d_ws;
  unsigned short* cpz = P + (size_t)2 * 8 * 1024 * 196;
  unsigned short* spz = cpz + (size_t)8 * 9 * 1024 * 16;

  proj_kernel<<<dim3(512), 256, 0, stream>>>(x, w1, b1, w2, b2, P);
  gather_kernel<<<dim3(1024), 256, 0, stream>>>(P, cpz, spz);
  cofe_kernel<<<dim3(2304), 512, 0, stream>>>(cpz, spz, out);
}